// Round 2
// baseline (7077.450 us; speedup 1.0000x reference)
//
#include <hip/hip_runtime.h>

// RStarcoderAttention: MoE-LoRA QKV proj + RoPE + causal flash attention + LoRA out proj.
// B=2 S=2048 E=2048 H=16 D=128 NE=8 R=16. fp32 accumulation everywhere.
// Round 2: dtype-ADAPTIVE (runtime-detect fp32 vs bf16 inputs/output via k_detect).
// Intermediates bf16 in ws (~68 MB).

#define B_ 2
#define S_ 2048
#define E_ 2048
#define H_ 16
#define D_ 128
#define NE_ 8
#define R_ 16
#define HD_ 2048
#define M_ 4096          // B*S tokens
#define KL_ 128          // NE*R

typedef unsigned short u16;
typedef unsigned int u32;

__device__ __forceinline__ float bf2f(u16 u) {
    union { u32 i; float f; } v; v.i = ((u32)u) << 16; return v.f;
}
__device__ __forceinline__ u16 f2bf(float f) {
    union { float f; u32 i; } v; v.f = f;
    u32 x = v.i;
    return (u16)((x + 0x7fffu + ((x >> 16) & 1u)) >> 16);   // RNE
}
__device__ __forceinline__ float ldf(const void* p, size_t i, int f) {
    return f ? ((const float*)p)[i] : bf2f(((const u16*)p)[i]);
}
__device__ __forceinline__ float4 ld4(const void* p, size_t i, int f) {
    if (f) return *(const float4*)((const float*)p + i);
    ushort4 v = *(const ushort4*)((const u16*)p + i);
    return make_float4(bf2f(v.x), bf2f(v.y), bf2f(v.z), bf2f(v.w));
}

// ---------------------------------------------------------------------------
// Detect input dtype. If x is packed bf16, the low u16 of each u32 word is a
// sane N(0,1) bf16 (exponent ~[110,140]). If x is fp32, the low u16 is random
// mantissa bits -> exponent uniform over 0..255 (~84% outside range).
// flags[0] = 1 for fp32, 0 for bf16.
__global__ void k_detect(const void* __restrict__ x, int* __restrict__ flags) {
    __shared__ int votes[2];
    int tid = threadIdx.x;
    if (tid < 2) votes[tid] = 0;
    __syncthreads();
    const u32* p = (const u32*)x;
    int bad = 0, tot = 0;
    for (int i = tid; i < 4096; i += 64) {
        u32 lo = p[i] & 0xffffu;
        if (lo) {
            tot++;
            int e = (int)((lo >> 7) & 0xffu);
            if (e < 100 || e > 150) bad++;
        }
    }
    atomicAdd(&votes[0], bad);
    atomicAdd(&votes[1], tot);
    __syncthreads();
    if (tid == 0) flags[0] = (votes[1] > 0 && votes[0] * 10 > votes[1] * 3) ? 1 : 0;
}

// ---------------------------------------------------------------------------
// Transpose A [NE*R=128, E] -> At [E, 128] (bf16) for coalesced LoRA access.
__global__ void k_transpose_a(const void* __restrict__ A, u16* __restrict__ At,
                              const int* __restrict__ flags) {
    int fin = flags[0];
    int idx = blockIdx.x * 256 + threadIdx.x;   // 0 .. 262143
    int i = idx >> 7, er = idx & 127;
    At[idx] = f2bf(ldf(A, (size_t)er * E_ + i, fin));
}

// ---------------------------------------------------------------------------
// hg[t][er] = (sum_i X[t][i] * At[i][er]) * mask[t][er>>4]   (hg bf16)
__global__ __launch_bounds__(256) void k_lora_h(
    const void* __restrict__ X, const u16* __restrict__ At,
    const void* __restrict__ mask, u16* __restrict__ hg,
    const int* __restrict__ flags, int x_typed) {
    __shared__ float Xs[16][33];
    __shared__ float As[32][128];
    int fin = flags[0];
    int fx = x_typed ? fin : 0;
    int tid = threadIdx.x;
    int t0 = blockIdx.x * 16;
    int er = tid & 127, half = tid >> 7;
    float acc[8];
#pragma unroll
    for (int i = 0; i < 8; i++) acc[i] = 0.f;

    for (int k0 = 0; k0 < E_; k0 += 32) {
        __syncthreads();
#pragma unroll
        for (int l = 0; l < 2; l++) {          // 16 tokens x 32 k
            int idx = l * 256 + tid; int tk = idx >> 5, kk = idx & 31;
            Xs[tk][kk] = ldf(X, (size_t)(t0 + tk) * E_ + k0 + kk, fx);
        }
#pragma unroll
        for (int l = 0; l < 16; l++) {         // 32 k x 128 er
            int idx = l * 256 + tid; int kk = idx >> 7, e = idx & 127;
            As[kk][e] = bf2f(At[(size_t)(k0 + kk) * 128 + e]);
        }
        __syncthreads();
#pragma unroll
        for (int kk = 0; kk < 32; kk++) {
            float a = As[kk][er];
#pragma unroll
            for (int tt = 0; tt < 8; tt++)
                acc[tt] += Xs[half * 8 + tt][kk] * a;
        }
    }
    int ne = er >> 4;
#pragma unroll
    for (int tt = 0; tt < 8; tt++) {
        int t = t0 + half * 8 + tt;
        float mv = ldf(mask, (size_t)t * NE_ + ne, fin);
        hg[(size_t)t * 128 + er] = f2bf(acc[tt] * mv);
    }
}

// ---------------------------------------------------------------------------
// Y[m][n] = sum_{k<2048} X[m][k] W[n][k] + sum_{k<128} hg[m][k] Bm[n][k] + bias[n]
// 64x64 tile per block, 256 threads, 4x4 micro-tile, K chunks of 16.
__global__ __launch_bounds__(256) void k_gemm(
    const void* __restrict__ X, const void* __restrict__ W,
    const u16* __restrict__ hg, const void* __restrict__ Bm,
    const void* __restrict__ bias, void* __restrict__ Y,
    const int* __restrict__ flags, int x_typed, int y_typed) {
    __shared__ float Xs[16][68];
    __shared__ float Ws[16][68];
    int fin = flags[0];
    int fx = x_typed ? fin : 0;
    int fy = y_typed ? fin : 0;
    int tid = threadIdx.x;
    int tx = tid & 15, ty = tid >> 4;
    int m0 = blockIdx.y * 64, n0 = blockIdx.x * 64;
    int lm = tid >> 2;          // 0..63 row within tile
    int lk = (tid & 3) * 4;     // 0,4,8,12

    float acc[4][4];
#pragma unroll
    for (int i = 0; i < 4; i++)
#pragma unroll
        for (int j = 0; j < 4; j++) acc[i][j] = 0.f;

    for (int k0 = 0; k0 < E_ + KL_; k0 += 16) {
        float4 xv, wv;
        if (k0 < E_) {
            xv = ld4(X, (size_t)(m0 + lm) * E_ + k0 + lk, fx);
            wv = ld4(W, (size_t)(n0 + lm) * E_ + k0 + lk, fin);
        } else {
            int kb = k0 - E_;
            xv = ld4(hg, (size_t)(m0 + lm) * KL_ + kb + lk, 0);
            wv = ld4(Bm, (size_t)(n0 + lm) * KL_ + kb + lk, fin);
        }
        __syncthreads();
        Xs[lk + 0][lm] = xv.x; Xs[lk + 1][lm] = xv.y;
        Xs[lk + 2][lm] = xv.z; Xs[lk + 3][lm] = xv.w;
        Ws[lk + 0][lm] = wv.x; Ws[lk + 1][lm] = wv.y;
        Ws[lk + 2][lm] = wv.z; Ws[lk + 3][lm] = wv.w;
        __syncthreads();
#pragma unroll
        for (int kk = 0; kk < 16; kk++) {
            float4 a = *(const float4*)&Xs[kk][ty * 4];
            float4 b = *(const float4*)&Ws[kk][tx * 4];
            float av[4] = { a.x, a.y, a.z, a.w };
            float bv[4] = { b.x, b.y, b.z, b.w };
#pragma unroll
            for (int i = 0; i < 4; i++)
#pragma unroll
                for (int j = 0; j < 4; j++)
                    acc[i][j] += av[i] * bv[j];
        }
    }
#pragma unroll
    for (int i = 0; i < 4; i++) {
        int m = m0 + ty * 4 + i;
        int nb = n0 + tx * 4;
#pragma unroll
        for (int j = 0; j < 4; j++) {
            float v = acc[i][j] + ldf(bias, (size_t)(nb + j), fin);
            if (fy) ((float*)Y)[(size_t)m * HD_ + nb + j] = v;
            else    ((u16*)Y)[(size_t)m * HD_ + nb + j] = f2bf(v);
        }
    }
}

// ---------------------------------------------------------------------------
// In-place RoPE on bf16 [B,S,H,D]. Each thread owns the pair (d2, d2+64):
//   out[d2]    = t[d2]*cos - t[d2+64]*sin
//   out[d2+64] = t[d2+64]*cos + t[d2]*sin     (cos/sin at freq index d%64 = d2)
__global__ void k_rope(u16* __restrict__ Y) {
    int idx = blockIdx.x * 256 + threadIdx.x;   // over B*S*H*64
    int d2 = idx & 63;
    int sh = idx >> 6;                           // (b*S+s)*H + h
    int s = (sh >> 4) & (S_ - 1);
    float inv = powf(10000.f, -(float)d2 * (1.f / 64.f));
    float fr = (float)s * inv;
    float c, sn;
    sincosf(fr, &sn, &c);
    size_t base = ((size_t)sh) << 7;
    float t0 = bf2f(Y[base + d2]);
    float t1 = bf2f(Y[base + d2 + 64]);
    Y[base + d2]      = f2bf(t0 * c - t1 * sn);
    Y[base + d2 + 64] = f2bf(t1 * c + t0 * sn);
}

// ---------------------------------------------------------------------------
// Flash causal attention, all operands bf16 intermediates [B,S,H*D].
// Block: 256 threads = 4 waves; wave w owns query q0+w; K/V chunks of 64 keys.
__global__ __launch_bounds__(256) void k_flash(
    const u16* __restrict__ Q, const u16* __restrict__ K,
    const u16* __restrict__ V, u16* __restrict__ O) {
    __shared__ float Ks[128 * 65];
    __shared__ u32  Vs[64 * 64];     // Vs[j*64+i] packs V[j][2i], V[j][2i+1]
    __shared__ float qs[4 * 128];
    __shared__ float ps[4 * 64];
    int tid = threadIdx.x;
    int w = tid >> 6, lane = tid & 63;
    int bh = blockIdx.y, b = bh >> 4, h = bh & 15;
    int q0 = blockIdx.x * 4;
    int q = q0 + w;
#pragma unroll
    for (int l = 0; l < 2; l++) {
        int idx = l * 256 + tid; int qq = idx >> 7, d = idx & 127;
        qs[qq * 128 + d] = bf2f(Q[((size_t)(b * S_ + q0 + qq)) * HD_ + h * D_ + d]);
    }
    float m = -30000.f, lsum = 0.f, o0 = 0.f, o1 = 0.f;
    int nch = q0 / 64 + 1;
    const float scale = 0.088388347648318447f;   // 1/sqrt(128)

    for (int c = 0; c < nch; c++) {
        int k0 = c * 64;
        __syncthreads();
#pragma unroll
        for (int l = 0; l < 32; l++) {                   // K chunk: 64 x 128
            int idx = l * 256 + tid; int j = idx >> 7, d = idx & 127;
            Ks[d * 65 + j] = bf2f(K[((size_t)(b * S_ + k0 + j)) * HD_ + h * D_ + d]);
        }
#pragma unroll
        for (int l = 0; l < 16; l++) {                   // V chunk as u32 pairs
            int idx = l * 256 + tid; int j = idx >> 6, i2 = idx & 63;
            Vs[j * 64 + i2] = *(const u32*)(V + ((size_t)(b * S_ + k0 + j)) * HD_ + h * D_ + 2 * i2);
        }
        __syncthreads();

        float s = 0.f;
#pragma unroll 8
        for (int d = 0; d < 128; d++)
            s += qs[w * 128 + d] * Ks[d * 65 + lane];
        s *= scale;
        int key = k0 + lane;
        if (key > q) s = -30000.f;

        float mc = s;
#pragma unroll
        for (int off = 32; off; off >>= 1) mc = fmaxf(mc, __shfl_xor(mc, off, 64));
        float mnew = fmaxf(m, mc);
        float alpha = __expf(m - mnew);
        float p = __expf(s - mnew);
        float psum = p;
#pragma unroll
        for (int off = 32; off; off >>= 1) psum += __shfl_xor(psum, off, 64);
        lsum = lsum * alpha + psum;
        o0 *= alpha; o1 *= alpha;
        m = mnew;
        ps[w * 64 + lane] = p;                 // same-wave LDS round-trip
#pragma unroll 8
        for (int j = 0; j < 64; j++) {
            float pj = ps[w * 64 + j];
            u32 vv = Vs[j * 64 + lane];
            union { u32 i; float f; } vlo, vhi;
            vlo.i = vv << 16;                  // V[j][2*lane]
            vhi.i = vv & 0xffff0000u;          // V[j][2*lane+1]
            o0 += pj * vlo.f;
            o1 += pj * vhi.f;
        }
    }
    float invl = 1.f / lsum;
    u32 outpk = (u32)f2bf(o0 * invl) | ((u32)f2bf(o1 * invl) << 16);
    *(u32*)(O + ((size_t)(b * S_ + q)) * HD_ + h * D_ + 2 * lane) = outpk;
}

// ---------------------------------------------------------------------------
extern "C" void kernel_launch(void* const* d_in, const int* in_sizes, int n_in,
                              void* d_out, int out_size, void* d_ws, size_t ws_size,
                              hipStream_t stream) {
    const void* x    = d_in[0];
    const void* mask = d_in[1];
    const void* Wq = d_in[2];  const void* bq = d_in[3];
    const void* Aq = d_in[4];  const void* Bq = d_in[5];
    const void* Wk = d_in[6];  const void* bk = d_in[7];
    const void* Ak = d_in[8];  const void* Bk = d_in[9];
    const void* Wv = d_in[10]; const void* bv = d_in[11];
    const void* Av = d_in[12]; const void* Bv = d_in[13];
    const void* Wo = d_in[14]; const void* bo = d_in[15];
    const void* Ao = d_in[16]; const void* Bo = d_in[17];

    char* ws = (char*)d_ws;
    int* flags = (int*)ws;
    u16* At_q = (u16*)(ws + (1ll << 20));          // 4 x 512 KB bf16
    u16* At_k = At_q + 262144;
    u16* At_v = At_k + 262144;
    u16* At_o = At_v + 262144;
    u16* hg   = (u16*)(ws + (3ll << 20));          // 1 MB, reused q/k/v/o
    u16* Qb   = (u16*)(ws + (4ll  << 20));         // 16 MB each
    u16* Kb   = (u16*)(ws + (20ll << 20));
    u16* Vb   = (u16*)(ws + (36ll << 20));
    u16* Ob   = (u16*)(ws + (52ll << 20));         // total 68 MB

    k_detect<<<1, 64, 0, stream>>>(x, flags);

    k_transpose_a<<<1024, 256, 0, stream>>>(Aq, At_q, flags);
    k_transpose_a<<<1024, 256, 0, stream>>>(Ak, At_k, flags);
    k_transpose_a<<<1024, 256, 0, stream>>>(Av, At_v, flags);
    k_transpose_a<<<1024, 256, 0, stream>>>(Ao, At_o, flags);

    dim3 gg(HD_ / 64, M_ / 64);

    k_lora_h<<<M_ / 16, 256, 0, stream>>>(x, At_q, mask, hg, flags, 1);
    k_gemm<<<gg, 256, 0, stream>>>(x, Wq, hg, Bq, bq, Qb, flags, 1, 0);
    k_rope<<<(M_ * HD_ / 2) / 256, 256, 0, stream>>>(Qb);

    k_lora_h<<<M_ / 16, 256, 0, stream>>>(x, At_k, mask, hg, flags, 1);
    k_gemm<<<gg, 256, 0, stream>>>(x, Wk, hg, Bk, bk, Kb, flags, 1, 0);
    k_rope<<<(M_ * HD_ / 2) / 256, 256, 0, stream>>>(Kb);

    k_lora_h<<<M_ / 16, 256, 0, stream>>>(x, At_v, mask, hg, flags, 1);
    k_gemm<<<gg, 256, 0, stream>>>(x, Wv, hg, Bv, bv, Vb, flags, 1, 0);

    dim3 gf(S_ / 4, B_ * H_);
    k_flash<<<gf, 256, 0, stream>>>(Qb, Kb, Vb, Ob);

    k_lora_h<<<M_ / 16, 256, 0, stream>>>(Ob, At_o, mask, hg, flags, 0);
    k_gemm<<<gg, 256, 0, stream>>>(Ob, Wo, hg, Bo, bo, d_out, flags, 0, 1);
}

// Round 3
// 3110.632 us; speedup vs baseline: 2.2752x; 2.2752x over previous
//
#include <hip/hip_runtime.h>

// RStarcoderAttention: MoE-LoRA QKV proj + RoPE + causal flash attention + LoRA out proj.
// B=2 S=2048 E=2048 H=16 D=128 NE=8 R=16. fp32 accumulation everywhere.
// Round 3: MFMA flash attention (16x16x32 bf16), V pre-transposed to [B*H*D, S].
// GEMMs still vector-ALU (next target). Inputs runtime-detected fp32/bf16.

#define B_ 2
#define S_ 2048
#define E_ 2048
#define H_ 16
#define D_ 128
#define NE_ 8
#define R_ 16
#define HD_ 2048
#define M_ 4096          // B*S tokens
#define KL_ 128          // NE*R

typedef unsigned short u16;
typedef unsigned int u32;
typedef __attribute__((ext_vector_type(8))) short bf16x8;
typedef __attribute__((ext_vector_type(4))) float f32x4;

__device__ __forceinline__ float bf2f(u16 u) {
    union { u32 i; float f; } v; v.i = ((u32)u) << 16; return v.f;
}
__device__ __forceinline__ u16 f2bf(float f) {
    union { float f; u32 i; } v; v.f = f;
    u32 x = v.i;
    return (u16)((x + 0x7fffu + ((x >> 16) & 1u)) >> 16);   // RNE
}
__device__ __forceinline__ float ldf(const void* p, size_t i, int f) {
    return f ? ((const float*)p)[i] : bf2f(((const u16*)p)[i]);
}
__device__ __forceinline__ float4 ld4(const void* p, size_t i, int f) {
    if (f) return *(const float4*)((const float*)p + i);
    ushort4 v = *(const ushort4*)((const u16*)p + i);
    return make_float4(bf2f(v.x), bf2f(v.y), bf2f(v.z), bf2f(v.w));
}

// ---------------------------------------------------------------------------
__global__ void k_detect(const void* __restrict__ x, int* __restrict__ flags) {
    __shared__ int votes[2];
    int tid = threadIdx.x;
    if (tid < 2) votes[tid] = 0;
    __syncthreads();
    const u32* p = (const u32*)x;
    int bad = 0, tot = 0;
    for (int i = tid; i < 4096; i += 64) {
        u32 lo = p[i] & 0xffffu;
        if (lo) {
            tot++;
            int e = (int)((lo >> 7) & 0xffu);
            if (e < 100 || e > 150) bad++;
        }
    }
    atomicAdd(&votes[0], bad);
    atomicAdd(&votes[1], tot);
    __syncthreads();
    if (tid == 0) flags[0] = (votes[1] > 0 && votes[0] * 10 > votes[1] * 3) ? 1 : 0;
}

// ---------------------------------------------------------------------------
__global__ void k_transpose_a(const void* __restrict__ A, u16* __restrict__ At,
                              const int* __restrict__ flags) {
    int fin = flags[0];
    int idx = blockIdx.x * 256 + threadIdx.x;
    int i = idx >> 7, er = idx & 127;
    At[idx] = f2bf(ldf(A, (size_t)er * E_ + i, fin));
}

// ---------------------------------------------------------------------------
__global__ __launch_bounds__(256) void k_lora_h(
    const void* __restrict__ X, const u16* __restrict__ At,
    const void* __restrict__ mask, u16* __restrict__ hg,
    const int* __restrict__ flags, int x_typed) {
    __shared__ float Xs[16][33];
    __shared__ float As[32][128];
    int fin = flags[0];
    int fx = x_typed ? fin : 0;
    int tid = threadIdx.x;
    int t0 = blockIdx.x * 16;
    int er = tid & 127, half = tid >> 7;
    float acc[8];
#pragma unroll
    for (int i = 0; i < 8; i++) acc[i] = 0.f;

    for (int k0 = 0; k0 < E_; k0 += 32) {
        __syncthreads();
#pragma unroll
        for (int l = 0; l < 2; l++) {
            int idx = l * 256 + tid; int tk = idx >> 5, kk = idx & 31;
            Xs[tk][kk] = ldf(X, (size_t)(t0 + tk) * E_ + k0 + kk, fx);
        }
#pragma unroll
        for (int l = 0; l < 16; l++) {
            int idx = l * 256 + tid; int kk = idx >> 7, e = idx & 127;
            As[kk][e] = bf2f(At[(size_t)(k0 + kk) * 128 + e]);
        }
        __syncthreads();
#pragma unroll
        for (int kk = 0; kk < 32; kk++) {
            float a = As[kk][er];
#pragma unroll
            for (int tt = 0; tt < 8; tt++)
                acc[tt] += Xs[half * 8 + tt][kk] * a;
        }
    }
    int ne = er >> 4;
#pragma unroll
    for (int tt = 0; tt < 8; tt++) {
        int t = t0 + half * 8 + tt;
        float mv = ldf(mask, (size_t)t * NE_ + ne, fin);
        hg[(size_t)t * 128 + er] = f2bf(acc[tt] * mv);
    }
}

// ---------------------------------------------------------------------------
__global__ __launch_bounds__(256) void k_gemm(
    const void* __restrict__ X, const void* __restrict__ W,
    const u16* __restrict__ hg, const void* __restrict__ Bm,
    const void* __restrict__ bias, void* __restrict__ Y,
    const int* __restrict__ flags, int x_typed, int y_typed) {
    __shared__ float Xs[16][68];
    __shared__ float Ws[16][68];
    int fin = flags[0];
    int fx = x_typed ? fin : 0;
    int fy = y_typed ? fin : 0;
    int tid = threadIdx.x;
    int tx = tid & 15, ty = tid >> 4;
    int m0 = blockIdx.y * 64, n0 = blockIdx.x * 64;
    int lm = tid >> 2;
    int lk = (tid & 3) * 4;

    float acc[4][4];
#pragma unroll
    for (int i = 0; i < 4; i++)
#pragma unroll
        for (int j = 0; j < 4; j++) acc[i][j] = 0.f;

    for (int k0 = 0; k0 < E_ + KL_; k0 += 16) {
        float4 xv, wv;
        if (k0 < E_) {
            xv = ld4(X, (size_t)(m0 + lm) * E_ + k0 + lk, fx);
            wv = ld4(W, (size_t)(n0 + lm) * E_ + k0 + lk, fin);
        } else {
            int kb = k0 - E_;
            xv = ld4(hg, (size_t)(m0 + lm) * KL_ + kb + lk, 0);
            wv = ld4(Bm, (size_t)(n0 + lm) * KL_ + kb + lk, fin);
        }
        __syncthreads();
        Xs[lk + 0][lm] = xv.x; Xs[lk + 1][lm] = xv.y;
        Xs[lk + 2][lm] = xv.z; Xs[lk + 3][lm] = xv.w;
        Ws[lk + 0][lm] = wv.x; Ws[lk + 1][lm] = wv.y;
        Ws[lk + 2][lm] = wv.z; Ws[lk + 3][lm] = wv.w;
        __syncthreads();
#pragma unroll
        for (int kk = 0; kk < 16; kk++) {
            float4 a = *(const float4*)&Xs[kk][ty * 4];
            float4 b = *(const float4*)&Ws[kk][tx * 4];
            float av[4] = { a.x, a.y, a.z, a.w };
            float bv[4] = { b.x, b.y, b.z, b.w };
#pragma unroll
            for (int i = 0; i < 4; i++)
#pragma unroll
                for (int j = 0; j < 4; j++)
                    acc[i][j] += av[i] * bv[j];
        }
    }
#pragma unroll
    for (int i = 0; i < 4; i++) {
        int m = m0 + ty * 4 + i;
        int nb = n0 + tx * 4;
#pragma unroll
        for (int j = 0; j < 4; j++) {
            float v = acc[i][j] + ldf(bias, (size_t)(nb + j), fin);
            if (fy) ((float*)Y)[(size_t)m * HD_ + nb + j] = v;
            else    ((u16*)Y)[(size_t)m * HD_ + nb + j] = f2bf(v);
        }
    }
}

// ---------------------------------------------------------------------------
__global__ void k_rope(u16* __restrict__ Y) {
    int idx = blockIdx.x * 256 + threadIdx.x;
    int d2 = idx & 63;
    int sh = idx >> 6;
    int s = (sh >> 4) & (S_ - 1);
    float inv = powf(10000.f, -(float)d2 * (1.f / 64.f));
    float fr = (float)s * inv;
    float c, sn;
    sincosf(fr, &sn, &c);
    size_t base = ((size_t)sh) << 7;
    float t0 = bf2f(Y[base + d2]);
    float t1 = bf2f(Y[base + d2 + 64]);
    Y[base + d2]      = f2bf(t0 * c - t1 * sn);
    Y[base + d2 + 64] = f2bf(t1 * c + t0 * sn);
}

// ---------------------------------------------------------------------------
// Vb [B,S,H*D] -> Vt [B*H*D, S]   (row = b*2048 + h*128 + d)
__global__ void k_transpose_v(const u16* __restrict__ Vb, u16* __restrict__ Vt) {
    __shared__ u16 t[32][33];
    int s0 = blockIdx.x * 32;
    int n0 = blockIdx.y * 32;
    int b  = blockIdx.z;
    int tx = threadIdx.x & 31, ty = threadIdx.x >> 5;   // 32 x 8
#pragma unroll
    for (int r = 0; r < 4; r++)
        t[ty + r * 8][tx] = Vb[((size_t)(b * S_ + s0 + ty + r * 8)) * HD_ + n0 + tx];
    __syncthreads();
#pragma unroll
    for (int r = 0; r < 4; r++)
        Vt[((size_t)(b * HD_ + n0 + ty + r * 8)) * S_ + s0 + tx] = t[tx][ty + r * 8];
}

// ---------------------------------------------------------------------------
// MFMA flash attention. Q,K [B,S,H*D] bf16 (post-rope); Vt [B*H*D,S] bf16.
// Block: 4 waves x 32 queries = 128-query tile; K/V chunks of 64 keys.
// Per wave-chunk: QK = 2mt x 4nt x 4ks MFMA(16x16x32); online softmax in
// C-layout regs (row=quad*4+reg); P via per-wave LDS (C->A layout); PV =
// 2ks x 8nt x 2mt MFMA. LDS ~54 KB -> 2 blocks/CU.
#define KS_ST 136   // Ks row stride (bf16): 128+8 -> 272 B (16B-mult)
#define VT_ST 72    // Vs/Ps row stride: 64+8 -> 144 B (16B-mult)
#define SCALE_ 0.088388347648318447f

__global__ __launch_bounds__(256, 2) void k_flash2(
    const u16* __restrict__ Q, const u16* __restrict__ K,
    const u16* __restrict__ Vt, u16* __restrict__ O) {
    __shared__ __align__(16) u16 Ks[64 * KS_ST];    // 17408 B
    __shared__ __align__(16) u16 Vs[128 * VT_ST];   // 18432 B
    __shared__ __align__(16) u16 Ps[128 * VT_ST];   // 18432 B (4 waves x 32 rows)
    int tid = threadIdx.x;
    int w = tid >> 6, lane = tid & 63;
    int l15 = lane & 15, quad = lane >> 4;
    int x = blockIdx.x, y = blockIdx.y;
    int bh = y, b = bh >> 4, h = bh & 15;
    int qb = (y < 16) ? x : (15 - x);     // heavy+light pairing across co-resident blocks
    int q0 = qb * 128;

    // Q A-frags in registers: qf[mt][ks], lane holds Q[q=l15][d=ks*32+quad*8 ..+7]
    bf16x8 qf[2][4];
    size_t baseQ = ((size_t)(b * S_ + q0 + w * 32)) * HD_ + h * D_;
#pragma unroll
    for (int mt = 0; mt < 2; mt++)
#pragma unroll
        for (int ks = 0; ks < 4; ks++)
            qf[mt][ks] = *(const bf16x8*)(Q + baseQ + (size_t)(mt * 16 + l15) * HD_ + ks * 32 + quad * 8);

    f32x4 of[2][8];
#pragma unroll
    for (int mt = 0; mt < 2; mt++)
#pragma unroll
        for (int nt = 0; nt < 8; nt++)
#pragma unroll
            for (int r = 0; r < 4; r++) of[mt][nt][r] = 0.f;
    float mrow[2][4], lrow[2][4];
#pragma unroll
    for (int mt = 0; mt < 2; mt++)
#pragma unroll
        for (int r = 0; r < 4; r++) { mrow[mt][r] = -30000.f; lrow[mt][r] = 0.f; }

    int nch = q0 / 64 + 2;
    for (int c = 0; c < nch; c++) {
        int k0 = c * 64;
        __syncthreads();                       // protect prior-chunk LDS reads
#pragma unroll
        for (int it = 0; it < 4; it++) {       // stage K (64x128) and V (128x64)
            int idx = it * 256 + tid;
            int row = idx >> 4, d8 = (idx & 15) * 8;
            *(bf16x8*)(Ks + row * KS_ST + d8) =
                *(const bf16x8*)(K + ((size_t)(b * S_ + k0 + row)) * HD_ + h * D_ + d8);
            int d = idx >> 3, kg = (idx & 7) * 8;
            *(bf16x8*)(Vs + d * VT_ST + kg) =
                *(const bf16x8*)(Vt + ((size_t)(bh * 128 + d)) * S_ + k0 + kg);
        }
        __syncthreads();

        // ---- QK^T: S = Q(32x128) . K^T(128x64)
        f32x4 sf[2][4];
#pragma unroll
        for (int mt = 0; mt < 2; mt++)
#pragma unroll
            for (int nt = 0; nt < 4; nt++)
#pragma unroll
                for (int r = 0; r < 4; r++) sf[mt][nt][r] = 0.f;
#pragma unroll
        for (int ks = 0; ks < 4; ks++) {
            int koff = ks * 32 + quad * 8;
            bf16x8 qa0 = qf[0][ks], qa1 = qf[1][ks];
#pragma unroll
            for (int nt = 0; nt < 4; nt++) {
                bf16x8 kb = *(const bf16x8*)(Ks + (nt * 16 + l15) * KS_ST + koff);
                sf[0][nt] = __builtin_amdgcn_mfma_f32_16x16x32_bf16(qa0, kb, sf[0][nt], 0, 0, 0);
                sf[1][nt] = __builtin_amdgcn_mfma_f32_16x16x32_bf16(qa1, kb, sf[1][nt], 0, 0, 0);
            }
        }

        // ---- online softmax (rows = quad*4+r), P -> LDS (bf16), O rescale
#pragma unroll
        for (int mt = 0; mt < 2; mt++) {
            int rowb = q0 + w * 32 + mt * 16 + quad * 4;
            float al[4];
#pragma unroll
            for (int nt = 0; nt < 4; nt++) {
                int key = k0 + nt * 16 + l15;
#pragma unroll
                for (int r = 0; r < 4; r++) {
                    float sv = sf[mt][nt][r] * SCALE_;
                    sf[mt][nt][r] = (key > rowb + r) ? -30000.f : sv;
                }
            }
#pragma unroll
            for (int r = 0; r < 4; r++) {
                float cmax = fmaxf(fmaxf(sf[mt][0][r], sf[mt][1][r]),
                                   fmaxf(sf[mt][2][r], sf[mt][3][r]));
                cmax = fmaxf(cmax, __shfl_xor(cmax, 1, 64));
                cmax = fmaxf(cmax, __shfl_xor(cmax, 2, 64));
                cmax = fmaxf(cmax, __shfl_xor(cmax, 4, 64));
                cmax = fmaxf(cmax, __shfl_xor(cmax, 8, 64));
                float mnew = fmaxf(mrow[mt][r], cmax);
                float a = __expf(mrow[mt][r] - mnew);
                mrow[mt][r] = mnew;
                al[r] = a;
                float psum = 0.f;
#pragma unroll
                for (int nt = 0; nt < 4; nt++) {
                    float p = __expf(sf[mt][nt][r] - mnew);
                    sf[mt][nt][r] = p;
                    psum += p;
                }
                psum += __shfl_xor(psum, 1, 64);
                psum += __shfl_xor(psum, 2, 64);
                psum += __shfl_xor(psum, 4, 64);
                psum += __shfl_xor(psum, 8, 64);
                lrow[mt][r] = lrow[mt][r] * a + psum;
            }
#pragma unroll
            for (int nt = 0; nt < 4; nt++)
#pragma unroll
                for (int r = 0; r < 4; r++)
                    Ps[(w * 32 + mt * 16 + quad * 4 + r) * VT_ST + nt * 16 + l15] =
                        f2bf(sf[mt][nt][r]);
#pragma unroll
            for (int nt = 0; nt < 8; nt++)
#pragma unroll
                for (int r = 0; r < 4; r++) of[mt][nt][r] *= al[r];
        }

        // ---- PV: O += P(32x64) . V(64x128)   (Ps is per-wave; no barrier)
#pragma unroll
        for (int ks2 = 0; ks2 < 2; ks2++) {
            int koff = ks2 * 32 + quad * 8;
            bf16x8 pa0 = *(const bf16x8*)(Ps + (w * 32 + l15) * VT_ST + koff);
            bf16x8 pa1 = *(const bf16x8*)(Ps + (w * 32 + 16 + l15) * VT_ST + koff);
#pragma unroll
            for (int nt = 0; nt < 8; nt++) {
                bf16x8 vb = *(const bf16x8*)(Vs + (nt * 16 + l15) * VT_ST + koff);
                of[0][nt] = __builtin_amdgcn_mfma_f32_16x16x32_bf16(pa0, vb, of[0][nt], 0, 0, 0);
                of[1][nt] = __builtin_amdgcn_mfma_f32_16x16x32_bf16(pa1, vb, of[1][nt], 0, 0, 0);
            }
        }
    }

    // ---- epilogue: O / l
#pragma unroll
    for (int mt = 0; mt < 2; mt++) {
        int rowb = q0 + w * 32 + mt * 16 + quad * 4;
#pragma unroll
        for (int r = 0; r < 4; r++) {
            float inv = 1.f / lrow[mt][r];
            size_t base = ((size_t)(b * S_ + rowb + r)) * HD_ + h * D_;
#pragma unroll
            for (int nt = 0; nt < 8; nt++)
                O[base + nt * 16 + l15] = f2bf(of[mt][nt][r] * inv);
        }
    }
}

// ---------------------------------------------------------------------------
extern "C" void kernel_launch(void* const* d_in, const int* in_sizes, int n_in,
                              void* d_out, int out_size, void* d_ws, size_t ws_size,
                              hipStream_t stream) {
    const void* x    = d_in[0];
    const void* mask = d_in[1];
    const void* Wq = d_in[2];  const void* bq = d_in[3];
    const void* Aq = d_in[4];  const void* Bq = d_in[5];
    const void* Wk = d_in[6];  const void* bk = d_in[7];
    const void* Ak = d_in[8];  const void* Bk = d_in[9];
    const void* Wv = d_in[10]; const void* bv = d_in[11];
    const void* Av = d_in[12]; const void* Bv = d_in[13];
    const void* Wo = d_in[14]; const void* bo = d_in[15];
    const void* Ao = d_in[16]; const void* Bo = d_in[17];

    char* ws = (char*)d_ws;
    int* flags = (int*)ws;
    u16* At_q = (u16*)(ws + (1ll << 20));
    u16* At_k = At_q + 262144;
    u16* At_v = At_k + 262144;
    u16* At_o = At_v + 262144;
    u16* hg   = (u16*)(ws + (3ll << 20));
    u16* Qb   = (u16*)(ws + (4ll  << 20));         // 16 MB each
    u16* Kb   = (u16*)(ws + (20ll << 20));
    u16* Vb   = (u16*)(ws + (36ll << 20));
    u16* Vt   = (u16*)(ws + (52ll << 20));
    u16* Ob   = Vb;                                 // reuse: Vb dead after transpose

    k_detect<<<1, 64, 0, stream>>>(x, flags);

    k_transpose_a<<<1024, 256, 0, stream>>>(Aq, At_q, flags);
    k_transpose_a<<<1024, 256, 0, stream>>>(Ak, At_k, flags);
    k_transpose_a<<<1024, 256, 0, stream>>>(Av, At_v, flags);
    k_transpose_a<<<1024, 256, 0, stream>>>(Ao, At_o, flags);

    dim3 gg(HD_ / 64, M_ / 64);

    k_lora_h<<<M_ / 16, 256, 0, stream>>>(x, At_q, mask, hg, flags, 1);
    k_gemm<<<gg, 256, 0, stream>>>(x, Wq, hg, Bq, bq, Qb, flags, 1, 0);
    k_rope<<<(M_ * HD_ / 2) / 256, 256, 0, stream>>>(Qb);

    k_lora_h<<<M_ / 16, 256, 0, stream>>>(x, At_k, mask, hg, flags, 1);
    k_gemm<<<gg, 256, 0, stream>>>(x, Wk, hg, Bk, bk, Kb, flags, 1, 0);
    k_rope<<<(M_ * HD_ / 2) / 256, 256, 0, stream>>>(Kb);

    k_lora_h<<<M_ / 16, 256, 0, stream>>>(x, At_v, mask, hg, flags, 1);
    k_gemm<<<gg, 256, 0, stream>>>(x, Wv, hg, Bv, bv, Vb, flags, 1, 0);

    k_transpose_v<<<dim3(S_ / 32, HD_ / 32, B_), 256, 0, stream>>>(Vb, Vt);

    k_flash2<<<dim3(16, 32), 256, 0, stream>>>(Qb, Kb, Vt, Ob);

    k_lora_h<<<M_ / 16, 256, 0, stream>>>(Ob, At_o, mask, hg, flags, 0);
    k_gemm<<<gg, 256, 0, stream>>>(Ob, Wo, hg, Bo, bo, d_out, flags, 0, 1);
}

// Round 4
// 917.660 us; speedup vs baseline: 7.7125x; 3.3897x over previous
//
#include <hip/hip_runtime.h>

// RStarcoderAttention: MoE-LoRA QKV proj + RoPE + causal flash attention + LoRA out proj.
// B=2 S=2048 E=2048 H=16 D=128 NE=8 R=16. fp32 accumulation everywhere.
// Round 4: all GEMMs (incl. LoRA-h) via MFMA bf16 16x16x32, m97-style 128x128 tile,
// BK=64, global_load_lds width-16 staging. Inputs pre-converted to bf16 (k_cvt).
// Flash attention MFMA (round 3). Inputs runtime-detected fp32/bf16.

#define B_ 2
#define S_ 2048
#define E_ 2048
#define H_ 16
#define D_ 128
#define NE_ 8
#define R_ 16
#define HD_ 2048
#define M_ 4096          // B*S tokens
#define KL_ 128          // NE*R

typedef unsigned short u16;
typedef unsigned int u32;
typedef __attribute__((ext_vector_type(8))) short bf16x8;
typedef __attribute__((ext_vector_type(4))) float f32x4;

typedef const __attribute__((address_space(1))) void gvoid_t;
typedef __attribute__((address_space(3))) void svoid_t;

__device__ __forceinline__ float bf2f(u16 u) {
    union { u32 i; float f; } v; v.i = ((u32)u) << 16; return v.f;
}
__device__ __forceinline__ u16 f2bf(float f) {
    union { float f; u32 i; } v; v.f = f;
    u32 x = v.i;
    return (u16)((x + 0x7fffu + ((x >> 16) & 1u)) >> 16);   // RNE
}
__device__ __forceinline__ float ldf(const void* p, size_t i, int f) {
    return f ? ((const float*)p)[i] : bf2f(((const u16*)p)[i]);
}
__device__ __forceinline__ float4 ld4(const void* p, size_t i, int f) {
    if (f) return *(const float4*)((const float*)p + i);
    ushort4 v = *(const ushort4*)((const u16*)p + i);
    return make_float4(bf2f(v.x), bf2f(v.y), bf2f(v.z), bf2f(v.w));
}

// ---------------------------------------------------------------------------
__global__ void k_detect(const void* __restrict__ x, int* __restrict__ flags) {
    __shared__ int votes[2];
    int tid = threadIdx.x;
    if (tid < 2) votes[tid] = 0;
    __syncthreads();
    const u32* p = (const u32*)x;
    int bad = 0, tot = 0;
    for (int i = tid; i < 4096; i += 64) {
        u32 lo = p[i] & 0xffffu;
        if (lo) {
            tot++;
            int e = (int)((lo >> 7) & 0xffu);
            if (e < 100 || e > 150) bad++;
        }
    }
    atomicAdd(&votes[0], bad);
    atomicAdd(&votes[1], tot);
    __syncthreads();
    if (tid == 0) flags[0] = (votes[1] > 0 && votes[0] * 10 > votes[1] * 3) ? 1 : 0;
}

// ---------------------------------------------------------------------------
// Convert n elements fp32/bf16 -> bf16 (4 per thread).
__global__ void k_cvt(const void* __restrict__ src, u16* __restrict__ dst, int n,
                      const int* __restrict__ flags) {
    int fin = flags[0];
    int i = (blockIdx.x * 256 + threadIdx.x) * 4;
    if (i >= n) return;
    float4 v = ld4(src, i, fin);
    ushort4 o;
    o.x = f2bf(v.x); o.y = f2bf(v.y); o.z = f2bf(v.z); o.w = f2bf(v.w);
    *(ushort4*)(dst + i) = o;
}

// ---------------------------------------------------------------------------
// MFMA GEMM: C[m][n] = sum_k A[m][k]*B[n][k] (+ lora: sum A2[m][k2]*B2[n][k2])
// (+ bias[n]) (* mask[m][n>>4]). A,B,A2,B2 bf16; C bf16 or fp32.
// 128x128 tile, 256 thr = 4 waves (2x2 of 64x64), BK=64, global_load_lds staging.
#define BM_ 128
#define BN_ 128
#define BK_ 64

__global__ __launch_bounds__(256, 2) void k_gemm_mfma(
    const u16* __restrict__ A, int lda,
    const u16* __restrict__ Bw, int ldb, int K1,
    const u16* __restrict__ A2, const u16* __restrict__ B2, int K2,
    const void* __restrict__ bias, const void* __restrict__ mask,
    void* __restrict__ C, int ldc, int store_f32,
    const int* __restrict__ flags) {
    __shared__ __align__(16) u16 As[BM_ * BK_];   // 16 KB
    __shared__ __align__(16) u16 Bs[BN_ * BK_];   // 16 KB
    int tid = threadIdx.x;
    int w = tid >> 6, lane = tid & 63;
    int l15 = lane & 15, quad = lane >> 4;
    int wm = w >> 1, wn = w & 1;
    int m0 = blockIdx.y * BM_, n0 = blockIdx.x * BN_;
    int lrow = lane >> 3;          // 0..7 within 8-row staging group
    int lcol = (lane & 7) * 8;     // k-offset within row

    f32x4 acc[4][4];
#pragma unroll
    for (int mt = 0; mt < 4; mt++)
#pragma unroll
        for (int nt = 0; nt < 4; nt++)
#pragma unroll
            for (int r = 0; r < 4; r++) acc[mt][nt][r] = 0.f;

    int n1 = K1 / BK_, n2 = K2 / BK_;
    int total = n1 + n2;
    for (int it = 0; it < total; it++) {
        const u16 *pa, *pb; int sa, sb, kb;
        if (it < n1) { pa = A;  sa = lda; pb = Bw; sb = ldb; kb = it * BK_; }
        else         { pa = A2; sa = K2;  pb = B2; sb = K2;  kb = (it - n1) * BK_; }
        __syncthreads();
#pragma unroll
        for (int i = 0; i < 4; i++) {
            int rowb = (w * 4 + i) * 8;
            int r = rowb + lrow;
            __builtin_amdgcn_global_load_lds(
                (gvoid_t*)(pa + (size_t)(m0 + r) * sa + kb + lcol),
                (svoid_t*)(As + rowb * BK_), 16, 0, 0);
            __builtin_amdgcn_global_load_lds(
                (gvoid_t*)(pb + (size_t)(n0 + r) * sb + kb + lcol),
                (svoid_t*)(Bs + rowb * BK_), 16, 0, 0);
        }
        __syncthreads();
#pragma unroll
        for (int kk = 0; kk < 2; kk++) {
            int ko = kk * 32 + quad * 8;
            bf16x8 af[4], bf[4];
#pragma unroll
            for (int mt = 0; mt < 4; mt++)
                af[mt] = *(const bf16x8*)(As + (wm * 64 + mt * 16 + l15) * BK_ + ko);
#pragma unroll
            for (int nt = 0; nt < 4; nt++)
                bf[nt] = *(const bf16x8*)(Bs + (wn * 64 + nt * 16 + l15) * BK_ + ko);
#pragma unroll
            for (int mt = 0; mt < 4; mt++)
#pragma unroll
                for (int nt = 0; nt < 4; nt++)
                    acc[mt][nt] = __builtin_amdgcn_mfma_f32_16x16x32_bf16(
                        af[mt], bf[nt], acc[mt][nt], 0, 0, 0);
        }
    }

    int fin = flags[0];
#pragma unroll
    for (int mt = 0; mt < 4; mt++) {
#pragma unroll
        for (int r = 0; r < 4; r++) {
            int m = m0 + wm * 64 + mt * 16 + quad * 4 + r;
#pragma unroll
            for (int nt = 0; nt < 4; nt++) {
                int n = n0 + wn * 64 + nt * 16 + l15;
                float v = acc[mt][nt][r];
                if (bias) v += ldf(bias, (size_t)n, fin);
                if (mask) v *= ldf(mask, (size_t)m * NE_ + (n >> 4), fin);
                if (store_f32) ((float*)C)[(size_t)m * ldc + n] = v;
                else           ((u16*)C)[(size_t)m * ldc + n] = f2bf(v);
            }
        }
    }
}

// ---------------------------------------------------------------------------
__global__ void k_rope(u16* __restrict__ Y) {
    int idx = blockIdx.x * 256 + threadIdx.x;
    int d2 = idx & 63;
    int sh = idx >> 6;
    int s = (sh >> 4) & (S_ - 1);
    float inv = powf(10000.f, -(float)d2 * (1.f / 64.f));
    float fr = (float)s * inv;
    float c, sn;
    sincosf(fr, &sn, &c);
    size_t base = ((size_t)sh) << 7;
    float t0 = bf2f(Y[base + d2]);
    float t1 = bf2f(Y[base + d2 + 64]);
    Y[base + d2]      = f2bf(t0 * c - t1 * sn);
    Y[base + d2 + 64] = f2bf(t1 * c + t0 * sn);
}

// ---------------------------------------------------------------------------
// Vb [B,S,H*D] -> Vt [B*H*D, S]
__global__ void k_transpose_v(const u16* __restrict__ Vb, u16* __restrict__ Vt) {
    __shared__ u16 t[32][33];
    int s0 = blockIdx.x * 32;
    int n0 = blockIdx.y * 32;
    int b  = blockIdx.z;
    int tx = threadIdx.x & 31, ty = threadIdx.x >> 5;   // 32 x 8
#pragma unroll
    for (int r = 0; r < 4; r++)
        t[ty + r * 8][tx] = Vb[((size_t)(b * S_ + s0 + ty + r * 8)) * HD_ + n0 + tx];
    __syncthreads();
#pragma unroll
    for (int r = 0; r < 4; r++)
        Vt[((size_t)(b * HD_ + n0 + ty + r * 8)) * S_ + s0 + tx] = t[tx][ty + r * 8];
}

// ---------------------------------------------------------------------------
// MFMA flash attention (round 3, unchanged).
#define KS_ST 136
#define VT_ST 72
#define SCALE_ 0.088388347648318447f

__global__ __launch_bounds__(256, 2) void k_flash2(
    const u16* __restrict__ Q, const u16* __restrict__ K,
    const u16* __restrict__ Vt, u16* __restrict__ O) {
    __shared__ __align__(16) u16 Ks[64 * KS_ST];
    __shared__ __align__(16) u16 Vs[128 * VT_ST];
    __shared__ __align__(16) u16 Ps[128 * VT_ST];
    int tid = threadIdx.x;
    int w = tid >> 6, lane = tid & 63;
    int l15 = lane & 15, quad = lane >> 4;
    int x = blockIdx.x, y = blockIdx.y;
    int bh = y, b = bh >> 4, h = bh & 15;
    int qb = (y < 16) ? x : (15 - x);
    int q0 = qb * 128;

    bf16x8 qf[2][4];
    size_t baseQ = ((size_t)(b * S_ + q0 + w * 32)) * HD_ + h * D_;
#pragma unroll
    for (int mt = 0; mt < 2; mt++)
#pragma unroll
        for (int ks = 0; ks < 4; ks++)
            qf[mt][ks] = *(const bf16x8*)(Q + baseQ + (size_t)(mt * 16 + l15) * HD_ + ks * 32 + quad * 8);

    f32x4 of[2][8];
#pragma unroll
    for (int mt = 0; mt < 2; mt++)
#pragma unroll
        for (int nt = 0; nt < 8; nt++)
#pragma unroll
            for (int r = 0; r < 4; r++) of[mt][nt][r] = 0.f;
    float mrow[2][4], lrow[2][4];
#pragma unroll
    for (int mt = 0; mt < 2; mt++)
#pragma unroll
        for (int r = 0; r < 4; r++) { mrow[mt][r] = -30000.f; lrow[mt][r] = 0.f; }

    int nch = q0 / 64 + 2;
    for (int c = 0; c < nch; c++) {
        int k0 = c * 64;
        __syncthreads();
#pragma unroll
        for (int it = 0; it < 4; it++) {
            int idx = it * 256 + tid;
            int row = idx >> 4, d8 = (idx & 15) * 8;
            *(bf16x8*)(Ks + row * KS_ST + d8) =
                *(const bf16x8*)(K + ((size_t)(b * S_ + k0 + row)) * HD_ + h * D_ + d8);
            int d = idx >> 3, kg = (idx & 7) * 8;
            *(bf16x8*)(Vs + d * VT_ST + kg) =
                *(const bf16x8*)(Vt + ((size_t)(bh * 128 + d)) * S_ + k0 + kg);
        }
        __syncthreads();

        f32x4 sf[2][4];
#pragma unroll
        for (int mt = 0; mt < 2; mt++)
#pragma unroll
            for (int nt = 0; nt < 4; nt++)
#pragma unroll
                for (int r = 0; r < 4; r++) sf[mt][nt][r] = 0.f;
#pragma unroll
        for (int ks = 0; ks < 4; ks++) {
            int koff = ks * 32 + quad * 8;
            bf16x8 qa0 = qf[0][ks], qa1 = qf[1][ks];
#pragma unroll
            for (int nt = 0; nt < 4; nt++) {
                bf16x8 kb = *(const bf16x8*)(Ks + (nt * 16 + l15) * KS_ST + koff);
                sf[0][nt] = __builtin_amdgcn_mfma_f32_16x16x32_bf16(qa0, kb, sf[0][nt], 0, 0, 0);
                sf[1][nt] = __builtin_amdgcn_mfma_f32_16x16x32_bf16(qa1, kb, sf[1][nt], 0, 0, 0);
            }
        }

#pragma unroll
        for (int mt = 0; mt < 2; mt++) {
            int rowb = q0 + w * 32 + mt * 16 + quad * 4;
            float al[4];
#pragma unroll
            for (int nt = 0; nt < 4; nt++) {
                int key = k0 + nt * 16 + l15;
#pragma unroll
                for (int r = 0; r < 4; r++) {
                    float sv = sf[mt][nt][r] * SCALE_;
                    sf[mt][nt][r] = (key > rowb + r) ? -30000.f : sv;
                }
            }
#pragma unroll
            for (int r = 0; r < 4; r++) {
                float cmax = fmaxf(fmaxf(sf[mt][0][r], sf[mt][1][r]),
                                   fmaxf(sf[mt][2][r], sf[mt][3][r]));
                cmax = fmaxf(cmax, __shfl_xor(cmax, 1, 64));
                cmax = fmaxf(cmax, __shfl_xor(cmax, 2, 64));
                cmax = fmaxf(cmax, __shfl_xor(cmax, 4, 64));
                cmax = fmaxf(cmax, __shfl_xor(cmax, 8, 64));
                float mnew = fmaxf(mrow[mt][r], cmax);
                float a = __expf(mrow[mt][r] - mnew);
                mrow[mt][r] = mnew;
                al[r] = a;
                float psum = 0.f;
#pragma unroll
                for (int nt = 0; nt < 4; nt++) {
                    float p = __expf(sf[mt][nt][r] - mnew);
                    sf[mt][nt][r] = p;
                    psum += p;
                }
                psum += __shfl_xor(psum, 1, 64);
                psum += __shfl_xor(psum, 2, 64);
                psum += __shfl_xor(psum, 4, 64);
                psum += __shfl_xor(psum, 8, 64);
                lrow[mt][r] = lrow[mt][r] * a + psum;
            }
#pragma unroll
            for (int nt = 0; nt < 4; nt++)
#pragma unroll
                for (int r = 0; r < 4; r++)
                    Ps[(w * 32 + mt * 16 + quad * 4 + r) * VT_ST + nt * 16 + l15] =
                        f2bf(sf[mt][nt][r]);
#pragma unroll
            for (int nt = 0; nt < 8; nt++)
#pragma unroll
                for (int r = 0; r < 4; r++) of[mt][nt][r] *= al[r];
        }

#pragma unroll
        for (int ks2 = 0; ks2 < 2; ks2++) {
            int koff = ks2 * 32 + quad * 8;
            bf16x8 pa0 = *(const bf16x8*)(Ps + (w * 32 + l15) * VT_ST + koff);
            bf16x8 pa1 = *(const bf16x8*)(Ps + (w * 32 + 16 + l15) * VT_ST + koff);
#pragma unroll
            for (int nt = 0; nt < 8; nt++) {
                bf16x8 vb = *(const bf16x8*)(Vs + (nt * 16 + l15) * VT_ST + koff);
                of[0][nt] = __builtin_amdgcn_mfma_f32_16x16x32_bf16(pa0, vb, of[0][nt], 0, 0, 0);
                of[1][nt] = __builtin_amdgcn_mfma_f32_16x16x32_bf16(pa1, vb, of[1][nt], 0, 0, 0);
            }
        }
    }

#pragma unroll
    for (int mt = 0; mt < 2; mt++) {
        int rowb = q0 + w * 32 + mt * 16 + quad * 4;
#pragma unroll
        for (int r = 0; r < 4; r++) {
            float inv = 1.f / lrow[mt][r];
            size_t base = ((size_t)(b * S_ + rowb + r)) * HD_ + h * D_;
#pragma unroll
            for (int nt = 0; nt < 8; nt++)
                O[base + nt * 16 + l15] = f2bf(of[mt][nt][r] * inv);
        }
    }
}

// ---------------------------------------------------------------------------
extern "C" void kernel_launch(void* const* d_in, const int* in_sizes, int n_in,
                              void* d_out, int out_size, void* d_ws, size_t ws_size,
                              hipStream_t stream) {
    const void* x    = d_in[0];
    const void* mask = d_in[1];
    const void* Wq = d_in[2];  const void* bq = d_in[3];
    const void* Aq = d_in[4];  const void* Bq = d_in[5];
    const void* Wk = d_in[6];  const void* bk = d_in[7];
    const void* Ak = d_in[8];  const void* Bk = d_in[9];
    const void* Wv = d_in[10]; const void* bv = d_in[11];
    const void* Av = d_in[12]; const void* Bv = d_in[13];
    const void* Wo = d_in[14]; const void* bo = d_in[15];
    const void* Ao = d_in[16]; const void* Bo = d_in[17];

    char* ws = (char*)d_ws;
    const long MB = 1 << 20;
    int* flags = (int*)ws;
    u16* Xb  = (u16*)(ws + 1  * MB);   // 16 MB  x as bf16
    u16* Ab  = (u16*)(ws + 17 * MB);   // 512 KB (A lora, reused)
    u16* Wb  = (u16*)(ws + 18 * MB);   // 8 MB   (W, reused)
    u16* Bmb = (u16*)(ws + 26 * MB);   // 512 KB (Bm, reused)
    u16* hgb = (u16*)(ws + 27 * MB);   // 1 MB   (lora h, reused)
    u16* Qb  = (u16*)(ws + 28 * MB);   // 16 MB each
    u16* Kb  = (u16*)(ws + 44 * MB);
    u16* Vb  = (u16*)(ws + 60 * MB);
    u16* Vt  = (u16*)(ws + 76 * MB);   // end 92 MB
    u16* Ob  = Vb;                     // Vb dead after transpose

    k_detect<<<1, 64, 0, stream>>>(x, flags);
    k_cvt<<<(M_ * E_) / 1024, 256, 0, stream>>>(x, Xb, M_ * E_, flags);

    dim3 gg(HD_ / BN_, M_ / BM_);       // (16, 32)
    dim3 gl(1, M_ / BM_);               // lora: N=128
    const int NW = E_ * HD_;            // 4 M
    const int NA = KL_ * E_;            // 256 K
    const int NB = HD_ * KL_;           // 256 K

    // ---- Q
    k_cvt<<<NA / 1024, 256, 0, stream>>>(Aq, Ab, NA, flags);
    k_gemm_mfma<<<gl, 256, 0, stream>>>(Xb, E_, Ab, E_, E_, nullptr, nullptr, 0,
                                        nullptr, mask, hgb, KL_, 0, flags);
    k_cvt<<<NW / 1024, 256, 0, stream>>>(Wq, Wb, NW, flags);
    k_cvt<<<NB / 1024, 256, 0, stream>>>(Bq, Bmb, NB, flags);
    k_gemm_mfma<<<gg, 256, 0, stream>>>(Xb, E_, Wb, E_, E_, hgb, Bmb, KL_,
                                        bq, nullptr, Qb, HD_, 0, flags);
    k_rope<<<(M_ * HD_ / 2) / 256, 256, 0, stream>>>(Qb);

    // ---- K
    k_cvt<<<NA / 1024, 256, 0, stream>>>(Ak, Ab, NA, flags);
    k_gemm_mfma<<<gl, 256, 0, stream>>>(Xb, E_, Ab, E_, E_, nullptr, nullptr, 0,
                                        nullptr, mask, hgb, KL_, 0, flags);
    k_cvt<<<NW / 1024, 256, 0, stream>>>(Wk, Wb, NW, flags);
    k_cvt<<<NB / 1024, 256, 0, stream>>>(Bk, Bmb, NB, flags);
    k_gemm_mfma<<<gg, 256, 0, stream>>>(Xb, E_, Wb, E_, E_, hgb, Bmb, KL_,
                                        bk, nullptr, Kb, HD_, 0, flags);
    k_rope<<<(M_ * HD_ / 2) / 256, 256, 0, stream>>>(Kb);

    // ---- V
    k_cvt<<<NA / 1024, 256, 0, stream>>>(Av, Ab, NA, flags);
    k_gemm_mfma<<<gl, 256, 0, stream>>>(Xb, E_, Ab, E_, E_, nullptr, nullptr, 0,
                                        nullptr, mask, hgb, KL_, 0, flags);
    k_cvt<<<NW / 1024, 256, 0, stream>>>(Wv, Wb, NW, flags);
    k_cvt<<<NB / 1024, 256, 0, stream>>>(Bv, Bmb, NB, flags);
    k_gemm_mfma<<<gg, 256, 0, stream>>>(Xb, E_, Wb, E_, E_, hgb, Bmb, KL_,
                                        bv, nullptr, Vb, HD_, 0, flags);

    k_transpose_v<<<dim3(S_ / 32, HD_ / 32, B_), 256, 0, stream>>>(Vb, Vt);

    // ---- attention
    k_flash2<<<dim3(16, 32), 256, 0, stream>>>(Qb, Kb, Vt, Ob);

    // ---- O projection
    k_cvt<<<NA / 1024, 256, 0, stream>>>(Ao, Ab, NA, flags);
    k_gemm_mfma<<<gl, 256, 0, stream>>>(Ob, HD_, Ab, E_, E_, nullptr, nullptr, 0,
                                        nullptr, mask, hgb, KL_, 0, flags);
    k_cvt<<<NW / 1024, 256, 0, stream>>>(Wo, Wb, NW, flags);
    k_cvt<<<NB / 1024, 256, 0, stream>>>(Bo, Bmb, NB, flags);
    k_gemm_mfma<<<gg, 256, 0, stream>>>(Ob, HD_, Wb, E_, E_, hgb, Bmb, KL_,
                                        bo, nullptr, d_out, HD_, 1, flags);
}